// Round 3
// baseline (321.569 us; speedup 1.0000x reference)
//
#include <hip/hip_runtime.h>
#include <stdint.h>

// Decomposition (unchanged):
//   UV[n][j] = z[n] . Wcat[:,j] (+ b1[j] for j<128), stored bf16, j in 0..255
//   out[e] = b2 + sum_j W2[j] * relu(UV[row[e]][j] + UV[col[e]][128+j])
//
// R5 change (edge kernel only; node kernel byte-identical to R4 winner):
//   Edge kernel is 217.6 of 317.6 us, running 764 MB of L2-miss gather traffic
//   at 3.69 TB/s effective (59% of streaming-achievable). Discriminating test:
//   2-edge unroll per 16-lane group with all 4 UV gathers in flight before any
//   use (per-wave in-flight gather bytes 512 B -> 1024 B). If MLP-bound, edge
//   drops toward ~170 us; if this is the random-256B fabric ceiling, unchanged
//   -> declare roofline next round.

typedef __attribute__((ext_vector_type(8))) short bf16x8;
typedef __attribute__((ext_vector_type(4))) float f32x4;

__device__ inline unsigned short f2bf(float f) {
    uint32_t u = __builtin_bit_cast(uint32_t, f);
    uint32_t r = (u + 0x7FFFu + ((u >> 16) & 1u)) >> 16;  // RNE
    return (unsigned short)r;
}

// ---------------- Kernel 1: node precompute via MFMA (R4 winner, unchanged) ---
__global__ __launch_bounds__(256) void node_precompute_mfma(
    const float* __restrict__ z, const float* __restrict__ W1,
    const float* __restrict__ b1, unsigned short* __restrict__ UV,
    int n_nodes)
{
    __shared__ __align__(16) char smem[4608 + 33792];
    typedef unsigned short us;
    us (*zs)[16][72] = (us(*)[16][72])smem;
    us (*w1s)[132]   = (us(*)[132])(smem + 4608);
    us (*uvs)[264]   = (us(*)[264])(smem + 4608);

    const int tid = threadIdx.x;
    const int w  = tid >> 6;    // wave 0..3
    const int l  = tid & 63;
    const int lm = l & 15;      // A-row / B-col / C-col sublane
    const int q  = l >> 4;      // quad 0..3

    // ---- one-time: stage W1 -> LDS bf16, coalesced float4 loads ----
    for (int i = tid; i < 128 * 32; i += 256) {
        const int r = i >> 5;
        const int c = (i & 31) * 4;
        const float4 v = *(const float4*)(W1 + (size_t)r * 128 + c);
        us* p = &w1s[r][c];
        p[0] = f2bf(v.x); p[1] = f2bf(v.y); p[2] = f2bf(v.z); p[3] = f2bf(v.w);
    }
    __syncthreads();

    // ---- B-fragments + per-col bias from LDS ----
    bf16x8 bfrag[4][2];
    float  bias[4];
#pragma unroll
    for (int nt = 0; nt < 4; ++nt) {
        const int n    = w * 64 + nt * 16 + lm;            // output col 0..255
        const int rr   = (n < 128) ? n : n - 128;
        const int koff = (n < 128) ? 0 : 64;
#pragma unroll
        for (int kh = 0; kh < 2; ++kh) {
            const int k0 = koff + kh * 32 + q * 8;
            bf16x8 bb;
#pragma unroll
            for (int j = 0; j < 8; ++j) bb[j] = (short)w1s[rr][k0 + j];
            bfrag[nt][kh] = bb;
        }
        bias[nt] = (n < 128) ? b1[n] : 0.f;
    }

    const int ntiles = (n_nodes + 15) >> 4;
    const int iters = (ntiles + gridDim.x - 1) / gridDim.x;  // uniform for barriers
    int tile = blockIdx.x;

    const int srow = tid >> 4;        // staging: thread -> (row, 4-float chunk)
    const int scol = (tid & 15) * 4;

    float4 zv = make_float4(0.f, 0.f, 0.f, 0.f);
    if (tile < ntiles && tile * 16 + srow < n_nodes)
        zv = *(const float4*)(z + (size_t)(tile * 16 + srow) * 64 + scol);

    for (int it = 0; it < iters; ++it) {
        const int buf = it & 1;
        const int node0 = tile * 16;

        if (tile < ntiles) {
            us* p = &zs[buf][srow][scol];
            p[0] = f2bf(zv.x); p[1] = f2bf(zv.y); p[2] = f2bf(zv.z); p[3] = f2bf(zv.w);
        }
        __syncthreads();   // (A)

        const int ntile = tile + gridDim.x;
        float4 zn = make_float4(0.f, 0.f, 0.f, 0.f);
        if (it + 1 < iters && ntile < ntiles && ntile * 16 + srow < n_nodes)
            zn = *(const float4*)(z + (size_t)(ntile * 16 + srow) * 64 + scol);

        if (tile < ntiles) {
            bf16x8 afrag[2];
#pragma unroll
            for (int kh = 0; kh < 2; ++kh)
                afrag[kh] = *(const bf16x8*)&zs[buf][lm][kh * 32 + q * 8];

            f32x4 acc[4];
#pragma unroll
            for (int nt = 0; nt < 4; ++nt) acc[nt] = (f32x4){0.f, 0.f, 0.f, 0.f};
#pragma unroll
            for (int kh = 0; kh < 2; ++kh)
#pragma unroll
                for (int nt = 0; nt < 4; ++nt)
                    acc[nt] = __builtin_amdgcn_mfma_f32_16x16x32_bf16(
                        afrag[kh], bfrag[nt][kh], acc[nt], 0, 0, 0);

#pragma unroll
            for (int nt = 0; nt < 4; ++nt) {
                const int ncol = w * 64 + nt * 16 + lm;
#pragma unroll
                for (int r = 0; r < 4; ++r)
                    uvs[q * 4 + r][ncol] = f2bf(acc[nt][r] + bias[nt]);
            }
        }
        __syncthreads();   // (B)

        if (tile < ntiles) {
#pragma unroll
            for (int h = 0; h < 2; ++h) {
                const int idx = h * 256 + tid;
                const int r   = idx >> 5;
                const int seg = idx & 31;
                const int node = node0 + r;
                if (node < n_nodes) {
                    const uint4 val = *(const uint4*)&uvs[r][seg * 8];
                    *(uint4*)(UV + (size_t)node * 256 + seg * 8) = val;
                }
            }
        }

        zv = zn;
        tile = ntile;
    }
}

// ---------------- Kernel 2: per-edge gather + relu + dot, 2-edge unroll -------
__device__ inline float acc2(uint32_t u, uint32_t v, float w0, float w1, float s) {
    float ul = __builtin_bit_cast(float, u << 16);
    float uh = __builtin_bit_cast(float, u & 0xFFFF0000u);
    float vl = __builtin_bit_cast(float, v << 16);
    float vh = __builtin_bit_cast(float, v & 0xFFFF0000u);
    s = fmaf(fmaxf(ul + vl, 0.f), w0, s);
    s = fmaf(fmaxf(uh + vh, 0.f), w1, s);
    return s;
}

__global__ __launch_bounds__(256) void edge_kernel(
    const unsigned short* __restrict__ UV,
    const int* __restrict__ row, const int* __restrict__ col,
    const float* __restrict__ W2, const float* __restrict__ b2,
    float* __restrict__ out, int E)
{
    const int sub = threadIdx.x & 15;           // lane within 16-lane edge-group
    const float4 w2a = *(const float4*)&W2[sub * 8];
    const float4 w2b = *(const float4*)&W2[sub * 8 + 4];
    const float bb = b2[0];

    const int G = gridDim.x * 16;               // total edge-groups in grid
    int g = blockIdx.x * 16 + (threadIdx.x >> 4);

    // main loop: 2 edges per iteration, all 4 gathers in flight before use
    for (; g + G < E; g += 2 * G) {
        const int g1 = g + G;
        const int r0 = row[g],  c0 = col[g];
        const int r1 = row[g1], c1 = col[g1];
        const uint4 uu0 = *(const uint4*)(UV + (size_t)r0 * 256 + sub * 8);
        const uint4 vv0 = *(const uint4*)(UV + (size_t)c0 * 256 + 128 + sub * 8);
        const uint4 uu1 = *(const uint4*)(UV + (size_t)r1 * 256 + sub * 8);
        const uint4 vv1 = *(const uint4*)(UV + (size_t)c1 * 256 + 128 + sub * 8);

        float s0 = 0.f;
        s0 = acc2(uu0.x, vv0.x, w2a.x, w2a.y, s0);
        s0 = acc2(uu0.y, vv0.y, w2a.z, w2a.w, s0);
        s0 = acc2(uu0.z, vv0.z, w2b.x, w2b.y, s0);
        s0 = acc2(uu0.w, vv0.w, w2b.z, w2b.w, s0);
        float s1 = 0.f;
        s1 = acc2(uu1.x, vv1.x, w2a.x, w2a.y, s1);
        s1 = acc2(uu1.y, vv1.y, w2a.z, w2a.w, s1);
        s1 = acc2(uu1.z, vv1.z, w2b.x, w2b.y, s1);
        s1 = acc2(uu1.w, vv1.w, w2b.z, w2b.w, s1);

        s0 += __shfl_xor(s0, 1, 16);
        s0 += __shfl_xor(s0, 2, 16);
        s0 += __shfl_xor(s0, 4, 16);
        s0 += __shfl_xor(s0, 8, 16);
        s1 += __shfl_xor(s1, 1, 16);
        s1 += __shfl_xor(s1, 2, 16);
        s1 += __shfl_xor(s1, 4, 16);
        s1 += __shfl_xor(s1, 8, 16);
        if (sub == 0) {
            out[g]  = s0 + bb;
            out[g1] = s1 + bb;
        }
    }
    // tail: at most one edge left for this group
    for (; g < E; g += G) {
        const int r = row[g];
        const int c = col[g];
        uint4 uu = *(const uint4*)(UV + (size_t)r * 256 + sub * 8);
        uint4 vv = *(const uint4*)(UV + (size_t)c * 256 + 128 + sub * 8);
        float s = 0.f;
        s = acc2(uu.x, vv.x, w2a.x, w2a.y, s);
        s = acc2(uu.y, vv.y, w2a.z, w2a.w, s);
        s = acc2(uu.z, vv.z, w2b.x, w2b.y, s);
        s = acc2(uu.w, vv.w, w2b.z, w2b.w, s);
        s += __shfl_xor(s, 1, 16);
        s += __shfl_xor(s, 2, 16);
        s += __shfl_xor(s, 4, 16);
        s += __shfl_xor(s, 8, 16);
        if (sub == 0) out[g] = s + bb;
    }
}

extern "C" void kernel_launch(void* const* d_in, const int* in_sizes, int n_in,
                              void* d_out, int out_size, void* d_ws, size_t ws_size,
                              hipStream_t stream) {
    const float* z   = (const float*)d_in[0];
    const int*   row = (const int*)d_in[1];
    const int*   col = (const int*)d_in[2];
    const float* W1  = (const float*)d_in[3];
    const float* b1  = (const float*)d_in[4];
    const float* W2  = (const float*)d_in[5];
    const float* b2  = (const float*)d_in[6];
    float* out = (float*)d_out;

    const int n_nodes = in_sizes[0] / 64;   // z is [N, 64]
    const int E = in_sizes[1];

    unsigned short* UV = (unsigned short*)d_ws;  // [n_nodes][256] bf16 = 51.2 MB

    node_precompute_mfma<<<1024, 256, 0, stream>>>(z, W1, b1, UV, n_nodes);

    edge_kernel<<<4096, 256, 0, stream>>>(UV, row, col, W2, b2, out, E);
}

// Round 4
// 316.858 us; speedup vs baseline: 1.0149x; 1.0149x over previous
//
#include <hip/hip_runtime.h>
#include <stdint.h>

// Decomposition (unchanged):
//   UV[n][j] = z[n] . Wcat[:,j] (+ b1[j] for j<128), stored bf16, j in 0..255
//   out[e] = b2 + sum_j W2[j] * relu(UV[row[e]][j] + UV[col[e]][128+j])
//
// R6: REVERT to the R2/R4-winner configuration (best measured: 317.6 us).
//   R3's 2-edge unroll was a confirmed negative (-5 us edge, occupancy 89->80,
//   strided out-writes +1.8 MB WRITE_SIZE) and refuted the MLP-bound
//   hypothesis: edge kernel is at the random-256B-gather fabric ceiling
//   (764 MB fabric traffic == algorithmic L2-miss minimum, 3.5-3.7 TB/s ==
//   56-59% of streaming-achievable, the expected random-granule derate).
//   Node kernel is within ~7 us of its 13 us memory floor; the ~80 us
//   residual is invariant harness reset-dispatch overhead.

typedef __attribute__((ext_vector_type(8))) short bf16x8;
typedef __attribute__((ext_vector_type(4))) float f32x4;

__device__ inline unsigned short f2bf(float f) {
    uint32_t u = __builtin_bit_cast(uint32_t, f);
    uint32_t r = (u + 0x7FFFu + ((u >> 16) & 1u)) >> 16;  // RNE
    return (unsigned short)r;
}

// ---------------- Kernel 1: node precompute via MFMA (R4 winner, unchanged) ---
__global__ __launch_bounds__(256) void node_precompute_mfma(
    const float* __restrict__ z, const float* __restrict__ W1,
    const float* __restrict__ b1, unsigned short* __restrict__ UV,
    int n_nodes)
{
    __shared__ __align__(16) char smem[4608 + 33792];
    typedef unsigned short us;
    us (*zs)[16][72] = (us(*)[16][72])smem;
    us (*w1s)[132]   = (us(*)[132])(smem + 4608);
    us (*uvs)[264]   = (us(*)[264])(smem + 4608);

    const int tid = threadIdx.x;
    const int w  = tid >> 6;    // wave 0..3
    const int l  = tid & 63;
    const int lm = l & 15;      // A-row / B-col / C-col sublane
    const int q  = l >> 4;      // quad 0..3

    // ---- one-time: stage W1 -> LDS bf16, coalesced float4 loads ----
    for (int i = tid; i < 128 * 32; i += 256) {
        const int r = i >> 5;
        const int c = (i & 31) * 4;
        const float4 v = *(const float4*)(W1 + (size_t)r * 128 + c);
        us* p = &w1s[r][c];
        p[0] = f2bf(v.x); p[1] = f2bf(v.y); p[2] = f2bf(v.z); p[3] = f2bf(v.w);
    }
    __syncthreads();

    // ---- B-fragments + per-col bias from LDS ----
    bf16x8 bfrag[4][2];
    float  bias[4];
#pragma unroll
    for (int nt = 0; nt < 4; ++nt) {
        const int n    = w * 64 + nt * 16 + lm;            // output col 0..255
        const int rr   = (n < 128) ? n : n - 128;
        const int koff = (n < 128) ? 0 : 64;
#pragma unroll
        for (int kh = 0; kh < 2; ++kh) {
            const int k0 = koff + kh * 32 + q * 8;
            bf16x8 bb;
#pragma unroll
            for (int j = 0; j < 8; ++j) bb[j] = (short)w1s[rr][k0 + j];
            bfrag[nt][kh] = bb;
        }
        bias[nt] = (n < 128) ? b1[n] : 0.f;
    }

    const int ntiles = (n_nodes + 15) >> 4;
    const int iters = (ntiles + gridDim.x - 1) / gridDim.x;  // uniform for barriers
    int tile = blockIdx.x;

    const int srow = tid >> 4;        // staging: thread -> (row, 4-float chunk)
    const int scol = (tid & 15) * 4;

    float4 zv = make_float4(0.f, 0.f, 0.f, 0.f);
    if (tile < ntiles && tile * 16 + srow < n_nodes)
        zv = *(const float4*)(z + (size_t)(tile * 16 + srow) * 64 + scol);

    for (int it = 0; it < iters; ++it) {
        const int buf = it & 1;
        const int node0 = tile * 16;

        if (tile < ntiles) {
            us* p = &zs[buf][srow][scol];
            p[0] = f2bf(zv.x); p[1] = f2bf(zv.y); p[2] = f2bf(zv.z); p[3] = f2bf(zv.w);
        }
        __syncthreads();   // (A)

        const int ntile = tile + gridDim.x;
        float4 zn = make_float4(0.f, 0.f, 0.f, 0.f);
        if (it + 1 < iters && ntile < ntiles && ntile * 16 + srow < n_nodes)
            zn = *(const float4*)(z + (size_t)(ntile * 16 + srow) * 64 + scol);

        if (tile < ntiles) {
            bf16x8 afrag[2];
#pragma unroll
            for (int kh = 0; kh < 2; ++kh)
                afrag[kh] = *(const bf16x8*)&zs[buf][lm][kh * 32 + q * 8];

            f32x4 acc[4];
#pragma unroll
            for (int nt = 0; nt < 4; ++nt) acc[nt] = (f32x4){0.f, 0.f, 0.f, 0.f};
#pragma unroll
            for (int kh = 0; kh < 2; ++kh)
#pragma unroll
                for (int nt = 0; nt < 4; ++nt)
                    acc[nt] = __builtin_amdgcn_mfma_f32_16x16x32_bf16(
                        afrag[kh], bfrag[nt][kh], acc[nt], 0, 0, 0);

#pragma unroll
            for (int nt = 0; nt < 4; ++nt) {
                const int ncol = w * 64 + nt * 16 + lm;
#pragma unroll
                for (int r = 0; r < 4; ++r)
                    uvs[q * 4 + r][ncol] = f2bf(acc[nt][r] + bias[nt]);
            }
        }
        __syncthreads();   // (B)

        if (tile < ntiles) {
#pragma unroll
            for (int h = 0; h < 2; ++h) {
                const int idx = h * 256 + tid;
                const int r   = idx >> 5;
                const int seg = idx & 31;
                const int node = node0 + r;
                if (node < n_nodes) {
                    const uint4 val = *(const uint4*)&uvs[r][seg * 8];
                    *(uint4*)(UV + (size_t)node * 256 + seg * 8) = val;
                }
            }
        }

        zv = zn;
        tile = ntile;
    }
}

// ---------------- Kernel 2: per-edge gather + relu + dot (R2 original) --------
__device__ inline float acc2(uint32_t u, uint32_t v, float w0, float w1, float s) {
    float ul = __builtin_bit_cast(float, u << 16);
    float uh = __builtin_bit_cast(float, u & 0xFFFF0000u);
    float vl = __builtin_bit_cast(float, v << 16);
    float vh = __builtin_bit_cast(float, v & 0xFFFF0000u);
    s = fmaf(fmaxf(ul + vl, 0.f), w0, s);
    s = fmaf(fmaxf(uh + vh, 0.f), w1, s);
    return s;
}

__global__ __launch_bounds__(256) void edge_kernel(
    const unsigned short* __restrict__ UV,
    const int* __restrict__ row, const int* __restrict__ col,
    const float* __restrict__ W2, const float* __restrict__ b2,
    float* __restrict__ out, int E)
{
    const int sub = threadIdx.x & 15;           // lane within 16-lane edge-group
    const float4 w2a = *(const float4*)&W2[sub * 8];
    const float4 w2b = *(const float4*)&W2[sub * 8 + 4];
    const float bb = b2[0];

    int g = blockIdx.x * 16 + (threadIdx.x >> 4);
    const int stride = gridDim.x * 16;

    for (; g < E; g += stride) {
        const int r = row[g];
        const int c = col[g];
        uint4 uu = *(const uint4*)(UV + (size_t)r * 256 + sub * 8);          // U half
        uint4 vv = *(const uint4*)(UV + (size_t)c * 256 + 128 + sub * 8);    // V half
        float s = 0.f;
        s = acc2(uu.x, vv.x, w2a.x, w2a.y, s);
        s = acc2(uu.y, vv.y, w2a.z, w2a.w, s);
        s = acc2(uu.z, vv.z, w2b.x, w2b.y, s);
        s = acc2(uu.w, vv.w, w2b.z, w2b.w, s);
        s += __shfl_xor(s, 1, 16);
        s += __shfl_xor(s, 2, 16);
        s += __shfl_xor(s, 4, 16);
        s += __shfl_xor(s, 8, 16);
        if (sub == 0) out[g] = s + bb;
    }
}

extern "C" void kernel_launch(void* const* d_in, const int* in_sizes, int n_in,
                              void* d_out, int out_size, void* d_ws, size_t ws_size,
                              hipStream_t stream) {
    const float* z   = (const float*)d_in[0];
    const int*   row = (const int*)d_in[1];
    const int*   col = (const int*)d_in[2];
    const float* W1  = (const float*)d_in[3];
    const float* b1  = (const float*)d_in[4];
    const float* W2  = (const float*)d_in[5];
    const float* b2  = (const float*)d_in[6];
    float* out = (float*)d_out;

    const int n_nodes = in_sizes[0] / 64;   // z is [N, 64]
    const int E = in_sizes[1];

    unsigned short* UV = (unsigned short*)d_ws;  // [n_nodes][256] bf16 = 51.2 MB

    node_precompute_mfma<<<1024, 256, 0, stream>>>(z, W1, b1, UV, n_nodes);

    edge_kernel<<<4096, 256, 0, stream>>>(UV, row, col, W2, b2, out, E);
}